// Round 9
// baseline (987.825 us; speedup 1.0000x reference)
//
#include <hip/hip_runtime.h>
#include <math.h>

// ---- problem dims ----
#define BB 32
#define CC 8
#define TT 20000
#define PP 25
#define LL 800          // T/P
#define CP 200          // C*P
#define DD 512
#define HH 8
#define MM 256
#define NLAYER 2
#define DHH 64
#define FF 1024
#define NCLS 10
#define HIDP 128
#define BL (BB*LL)      // 25600
#define KPATCH 256      // C*P=200 zero-padded to 256

// wtall element offsets (all transposed weights, bf16)
#define WT_PATCH 0
#define WT_QKV0  131072
#define WT_OW0   917504
#define WT_F10   1179648
#define WT_F20   1703936
#define WT_QKV1  2228224
#define WT_OW1   3014656
#define WT_F11   3276800
#define WT_F21   3801088
#define WT_POOL  4325376
#define WT_TOTAL 4390912
#define NUC 5120        // packed uvec/cvec width: qkv0|f1_0|qkv1|f1_1

typedef unsigned short u16;
typedef unsigned int u32;
typedef __attribute__((ext_vector_type(8))) short short8;
typedef __attribute__((ext_vector_type(4))) float f32x4;

// bf16 <-> fp32 helpers
__device__ __forceinline__ float b2f(u16 v) { return __uint_as_float(((u32)v) << 16); }
__device__ __forceinline__ float b2f_lo(u32 u) { return __uint_as_float(u << 16); }
__device__ __forceinline__ float b2f_hi(u32 u) { return __uint_as_float(u & 0xFFFF0000u); }
__device__ __forceinline__ u16 f2b(float f) {
  u32 u = __float_as_uint(f);
  u32 r = u + 0x7FFFu + ((u >> 16) & 1u);
  return (u16)(r >> 16);
}
// dual-dtype external read: flag=0 fp32, flag=1 bf16
__device__ __forceinline__ float ldx(const void* p, size_t i, int flag) {
  return flag ? b2f(((const u16*)p)[i]) : ((const float*)p)[i];
}
// async global->LDS, 16B per lane; lds dest = wave-uniform base + lane*16
typedef const __attribute__((address_space(1))) u32 gas_u32;
typedef __attribute__((address_space(3))) u32 las_u32;
__device__ __forceinline__ void gload16(const void* g, void* l) {
  __builtin_amdgcn_global_load_lds((gas_u32*)(size_t)g, (las_u32*)(size_t)l, 16, 0, 0);
}

// ---------------- dtype sniffer: patch_g is all-ones ----------------
__global__ void sniff_kernel(const u32* __restrict__ g, u32* __restrict__ flagp) {
  if (threadIdx.x == 0) flagp[0] = (g[0] == 0x3F800000u) ? 0u : 1u;
}

__global__ void sentinel_kernel(u16* out, int n) {
  int i = blockIdx.x * 256 + threadIdx.x;
  if (i < n) out[i] = f2b(1.0e9f);
}

// ---------------- patchify: x(B,C,T) -> tok(B*L, 256) bf16, cols>=200 zero ----------------
__global__ void patchify_kernel(const void* __restrict__ x, u16* __restrict__ tok,
                                const u32* __restrict__ dflag) {
  int flag = (int)dflag[0];
  int idx = blockIdx.x * 256 + threadIdx.x;
  if (idx >= BL * KPATCH) return;
  int col = idx & (KPATCH - 1), row = idx >> 8;
  if (col >= CP) { tok[idx] = 0; return; }
  int b = row / LL, l = row % LL;
  int c = col / PP, p = col % PP;
  tok[idx] = f2b(ldx(x, ((size_t)b * CC + c) * TT + l * PP + p, flag));
}

// ---------------- omega -> bf16 * 64^-0.25, transposed [l][feat][k] ----------------
__global__ void omcvt_kernel(const void* __restrict__ om, u16* __restrict__ ombT,
                             const u32* __restrict__ dflag) {
  int flag = (int)dflag[0];
  const float inv4 = 0.35355339059327373f;  // 64^-0.25
  int idx = blockIdx.x * 256 + threadIdx.x;
  if (idx >= NLAYER * MM * DHH) return;
  int l = idx >> 14;          // / (MM*DHH)
  int r = idx & (MM * DHH - 1);
  int feat = r >> 6, k = r & 63;
  ombT[idx] = f2b(inv4 * ldx(om, (size_t)l * DHH * MM + (size_t)k * MM + feat, flag));
}

// ---------------- mega weight-transpose: ALL matrices in one dispatch ----------------
// Wt[n][k] = g[k]*W[woff + k*N + n]; pU[ky][ucoff+n] = sum_k g_k W_kn (stride NUC).
struct Seg { int t0, wsel, gsel, woff, goff, wtoff, ucoff, K, N, Kp; };
__constant__ Seg g_segs[14] = {
  {   0, 0, -1,      0,   0, WT_PATCH,          -1,  200,  512,  256},
  {  32, 2,  0,      0,   0, WT_QKV0,             0,  512,  512,  512},
  {  96, 3,  0,      0,   0, WT_QKV0 + 262144,  512,  512,  512,  512},
  { 160, 1,  0,      0,   0, WT_QKV0 + 524288, 1024,  512,  512,  512},
  { 224, 4, -1,      0,   0, WT_OW0,            -1,  512,  512,  512},
  { 288, 5,  1,      0,   0, WT_F10,           1536,  512, 1024,  512},
  { 416, 6, -1,      0,   0, WT_F20,            -1, 1024,  512, 1024},
  { 544, 2,  0, 262144, 512, WT_QKV1,          2560,  512,  512,  512},
  { 608, 3,  0, 262144, 512, WT_QKV1 + 262144, 3072,  512,  512,  512},
  { 672, 1,  0, 262144, 512, WT_QKV1 + 524288, 3584,  512,  512,  512},
  { 736, 4, -1, 262144,   0, WT_OW1,            -1,  512,  512,  512},
  { 800, 5,  1, 524288, 512, WT_F11,           4096,  512, 1024,  512},
  { 928, 6, -1, 524288,   0, WT_F21,            -1, 1024,  512, 1024},
  {1056, 7, -1,      0,   0, WT_POOL,           -1,  512,  128,  512},
};

__global__ __launch_bounds__(256) void megawt_kernel(
    const void* __restrict__ patchW, const void* __restrict__ qW,
    const void* __restrict__ kW, const void* __restrict__ vW,
    const void* __restrict__ oW, const void* __restrict__ f1W,
    const void* __restrict__ f2W, const void* __restrict__ poolW1,
    const void* __restrict__ ln1g, const void* __restrict__ ln1b,
    const void* __restrict__ ln2g, const void* __restrict__ ln2b,
    u16* __restrict__ wtall, float* __restrict__ pU, float* __restrict__ pC,
    const u32* __restrict__ dflag) {
  int flag = (int)dflag[0];
  int bid = blockIdx.x;
  int si = 0;
#pragma unroll
  for (int i = 1; i < 14; i++) if (bid >= g_segs[i].t0) si = i;
  Seg sg = g_segs[si];
  const void* W = (sg.wsel == 0) ? patchW : (sg.wsel == 1) ? qW : (sg.wsel == 2) ? kW
               : (sg.wsel == 3) ? vW : (sg.wsel == 4) ? oW : (sg.wsel == 5) ? f1W
               : (sg.wsel == 6) ? f2W : poolW1;
  const void* gv = (sg.gsel == 0) ? ln1g : (sg.gsel == 1) ? ln2g : nullptr;
  const void* bv = (sg.gsel == 0) ? ln1b : (sg.gsel == 1) ? ln2b : nullptr;
  int lt = bid - sg.t0;
  int nx = sg.N >> 6;
  int n0 = (lt % nx) * 64, k0 = (lt / nx) * 64;
  bool hasU = sg.ucoff >= 0;

  __shared__ float tile[64][65];
  __shared__ float sU[4][64], sC[4][64];
  int tn = threadIdx.x & 63;
  int tk = threadIdx.x >> 6;
  float su = 0.f, sc = 0.f;
#pragma unroll 4
  for (int i = 0; i < 16; i++) {
    int k = k0 + tk * 16 + i;
    float gw = 0.f;
    if (k < sg.K) {
      float w = ldx(W, (size_t)sg.woff + (size_t)k * sg.N + n0 + tn, flag);
      float g = gv ? ldx(gv, (size_t)sg.goff + k, flag) : 1.0f;
      gw = g * w;
      if (hasU) {
        su += gw;
        sc = fmaf(ldx(bv, (size_t)sg.goff + k, flag), w, sc);
      }
    }
    tile[tk * 16 + i][tn] = gw;
  }
  if (hasU) { sU[tk][tn] = su; sC[tk][tn] = sc; }
  __syncthreads();
  if (hasU && tk == 0) {
    pU[(size_t)(k0 >> 6) * NUC + sg.ucoff + n0 + tn] =
        sU[0][tn] + sU[1][tn] + sU[2][tn] + sU[3][tn];
    pC[(size_t)(k0 >> 6) * NUC + sg.ucoff + n0 + tn] =
        sC[0][tn] + sC[1][tn] + sC[2][tn] + sC[3][tn];
  }
#pragma unroll 4
  for (int i = 0; i < 16; i++) {
    int n = n0 + tk * 16 + i;
    wtall[(size_t)sg.wtoff + (size_t)n * sg.Kp + k0 + tn] = f2b(tile[tn][tk * 16 + i]);
  }
}

// reduce 8 partials -> u,c (N = NUC, one dispatch for everything)
__global__ __launch_bounds__(256) void ucr_kernel(const float* __restrict__ pU,
    const float* __restrict__ pC, float* __restrict__ u, float* __restrict__ c, int N) {
  int n = blockIdx.x * 256 + threadIdx.x;
  if (n >= N) return;
  float su = 0.f, sc = 0.f;
#pragma unroll
  for (int ky = 0; ky < 8; ky++) {
    su += pU[(size_t)ky * N + n];
    sc += pC[(size_t)ky * N + n];
  }
  u[n] = su;
  c[n] = sc;
}

// ---------------- MFMA GEMM: out = act(epi(A @ Wt^T) + bias) [+ res] ----------------
// 128x128 tile, BK=64, 4 waves. XCD-aware block swizzle. LDS C-tile repack store.
// LNE: 0 none; 1 stats from muv/rinvv arrays; 2 stats derived from 8-slot partials.
// STATS: epilogue writes per-row partial sum/sumsq of the ROUNDED stored values.
// SCORE: (pool path, N=128) epilogue computes scores[row] = dot(Cs row, bias[0..127])
//        and skips the global tile store entirely (output consumed only by softmax).
template<int ACT, bool HAS_BIAS, bool HAS_RES, int LNE, bool SPLIT3, bool STATS, bool SCORE>
__global__ __launch_bounds__(256, 4) void mgemm(
    const u16* __restrict__ A, const u16* __restrict__ Wt,
    const void* __restrict__ bias, size_t biasoff,
    const float* __restrict__ stA, const float* __restrict__ stB,
    const float* __restrict__ uvec, const float* __restrict__ cvec,
    const u16* res, u16* out, u16* out2, u16* out3,
    float* __restrict__ oSum, float* __restrict__ oSsq,
    int Kp, int N, const u32* __restrict__ dflag) {
  const int flag = (int)dflag[0];
  alignas(16) __shared__ u16 smem[128 * 128];   // As | Bs during K-loop; C-tile in epilogue
  __shared__ float statL[256];                  // [0..127] mu, [128..255] rinv
  u16* As = smem;
  u16* Bs = smem + 128 * 64;
  int tid = threadIdx.x;
  // XCD-aware swizzle (gridDim.y % 8 == 0 for all call sites)
  int flat = blockIdx.y * gridDim.x + blockIdx.x;
  int xcd = flat & 7;
  int p_ = flat >> 3;
  int gx = gridDim.x;
  int mtile = xcd * (gridDim.y >> 3) + p_ / gx;
  int ntile = p_ % gx;
  int m0 = mtile * 128, n0 = ntile * 128;
  int wid = tid >> 6, lane = tid & 63;
  int wm = (wid >> 1) * 64, wn = (wid & 1) * 64;
  int quad = lane >> 4, cl = lane & 15;

  if (LNE == 1) {
    if (tid < 128) {
      statL[tid] = stA[m0 + tid];
      statL[128 + tid] = stB[m0 + tid];
    }
  } else if (LNE == 2) {
    if (tid < 128) {
      float s = 0.f, q = 0.f;
#pragma unroll
      for (int s8 = 0; s8 < 8; s8++) {
        s += stA[(size_t)s8 * BL + m0 + tid];
        q += stB[(size_t)s8 * BL + m0 + tid];
      }
      float mu = s * (1.f / DD);
      float var = q * (1.f / DD) - mu * mu;
      statL[tid] = mu;
      statL[128 + tid] = 1.0f / sqrtf(var + 1e-5f);
    }
  }

  f32x4 acc[4][4] = {};
  int r_ = tid >> 3, c_ = tid & 7;
  for (int k0 = 0; k0 < Kp; k0 += 64) {
    __syncthreads();
#pragma unroll
    for (int p = 0; p < 4; p++) {
      int row = p * 32 + r_;
      int gc = (c_ ^ (row & 7)) * 8;
      int lbase = ((p * 256 + (tid & ~63)) * 8);
      gload16(A + (size_t)(m0 + row) * Kp + k0 + gc, &As[lbase]);
      gload16(Wt + (size_t)(n0 + row) * Kp + k0 + gc, &Bs[lbase]);
    }
    __syncthreads();
#pragma unroll
    for (int kk = 0; kk < 64; kk += 32) {
      int qb = (kk >> 3) + quad;
      short8 af[4], bf[4];
#pragma unroll
      for (int mt = 0; mt < 4; mt++) {
        int arow = wm + mt * 16 + cl;
        af[mt] = *(const short8*)(&As[(arow * 8 + (qb ^ (cl & 7))) * 8]);
      }
#pragma unroll
      for (int nt = 0; nt < 4; nt++) {
        int brow = wn + nt * 16 + cl;
        bf[nt] = *(const short8*)(&Bs[(brow * 8 + (qb ^ (cl & 7))) * 8]);
      }
#pragma unroll
      for (int mt = 0; mt < 4; mt++)
#pragma unroll
        for (int nt = 0; nt < 4; nt++)
          acc[mt][nt] = __builtin_amdgcn_mfma_f32_16x16x32_bf16(
              af[mt], bf[nt], acc[mt][nt], 0, 0, 0);
    }
  }
  // ---- epilogue: compute final bf16 values into LDS tile ----
  __syncthreads();
  u16* Cs = smem;  // 128 x 128 bf16, row-major
  float sA[4][4] = {}, qA[4][4] = {};
#pragma unroll
  for (int nt = 0; nt < 4; nt++) {
    int tcol = wn + nt * 16 + cl;
    int gcol = n0 + tcol;
    float bvv = HAS_BIAS ? ldx(bias, biasoff + gcol, flag) : 0.f;
    float uv_ = 0.f, cv_ = 0.f;
    if (LNE) { uv_ = uvec[gcol]; cv_ = cvec[gcol]; }
#pragma unroll
    for (int mt = 0; mt < 4; mt++) {
#pragma unroll
      for (int r = 0; r < 4; r++) {
        int trow = wm + mt * 16 + quad * 4 + r;
        int grow = m0 + trow;
        float v = acc[mt][nt][r];
        if (LNE) {
          float rv_ = statL[128 + trow];
          v = rv_ * v - rv_ * statL[trow] * uv_ + cv_;
        }
        v += bvv;
        if (ACT == 1) v = 0.5f * v * (1.0f + erff(v * 0.7071067811865476f));
        else if (ACT == 2) v = tanhf(v);
        if (HAS_RES) v += b2f(res[(size_t)grow * N + gcol]);
        u16 wv = f2b(v);
        Cs[trow * 128 + tcol] = wv;
        if (STATS) {
          float vr = b2f(wv);
          sA[mt][r] += vr;
          qA[mt][r] += vr * vr;
        }
      }
    }
  }
  if (STATS) {
#pragma unroll
    for (int mt = 0; mt < 4; mt++)
#pragma unroll
      for (int r = 0; r < 4; r++) {
        float s = sA[mt][r], q = qA[mt][r];
        s += __shfl_xor(s, 1, 64); s += __shfl_xor(s, 2, 64);
        s += __shfl_xor(s, 4, 64); s += __shfl_xor(s, 8, 64);
        q += __shfl_xor(q, 1, 64); q += __shfl_xor(q, 2, 64);
        q += __shfl_xor(q, 4, 64); q += __shfl_xor(q, 8, 64);
        if (cl == 0) {
          int grow = m0 + wm + mt * 16 + quad * 4 + r;
          int slot = ntile * 2 + (wid & 1);
          oSum[(size_t)slot * BL + grow] = s;
          oSsq[(size_t)slot * BL + grow] = q;
        }
      }
  }
  __syncthreads();
  if (SCORE) {
    // pool path: N==128 so this block holds full rows; scores[grow] = Cs row . w2
    // column order staggered by row to avoid same-bank LDS reads across lanes.
    int row = tid >> 1, half = tid & 1;
    float p = 0.f;
#pragma unroll
    for (int j = 0; j < 64; j++) {
      int col = (half << 6) | ((j + row) & 63);
      p += b2f(Cs[row * 128 + col]) * ldx(bias, col, flag);
    }
    p += __shfl_xor(p, 1, 64);
    if (half == 0) oSum[m0 + row] = p;
  } else {
    // ---- coalesced store: each wave writes 4 rows x 256B contiguous per instr ----
    u16* dstbuf;
    int colbase, stride;
    if (SPLIT3) {
      int sel = n0 >> 9;
      dstbuf = (sel == 0) ? out : (sel == 1) ? out2 : out3;
      colbase = n0 & 511;
      stride = 512;
    } else {
      dstbuf = out;
      colbase = n0;
      stride = N;
    }
    int c8 = (tid & 15) * 8, rb = tid >> 4;
#pragma unroll
    for (int i = 0; i < 8; i++) {
      int trow = i * 16 + rb;
      uint4 vv = *(const uint4*)(&Cs[trow * 128 + c8]);
      *(uint4*)(&dstbuf[(size_t)(m0 + trow) * stride + colbase + c8]) = vv;
    }
  }
}

// ---------------- LN apply (patch LN): stats-in from pS partials, stats-out of h ----------------
__global__ __launch_bounds__(256) void ln_apply_kernel(const u16* __restrict__ x,
    const float* __restrict__ pSum, const float* __restrict__ pSsq,
    const void* __restrict__ g, const void* __restrict__ b, u16* __restrict__ out,
    float* __restrict__ muv, float* __restrict__ rinvv,
    const u32* __restrict__ dflag) {
  int flag = (int)dflag[0];
  int row = blockIdx.x * 4 + (threadIdx.x >> 6);
  int lane = threadIdx.x & 63;
  // input stats from 8 partial slots (broadcast loads)
  float s = 0.f, q = 0.f;
#pragma unroll
  for (int s8 = 0; s8 < 8; s8++) {
    s += pSum[(size_t)s8 * BL + row];
    q += pSsq[(size_t)s8 * BL + row];
  }
  float m = s * (1.f / DD);
  float var = q * (1.f / DD) - m * m;
  float rvv = 1.0f / sqrtf(var + 1e-5f);

  const u16* xr = x + (size_t)row * DD + lane * 8;
  uint4 u = *(const uint4*)xr;
  float f[8] = {b2f_lo(u.x), b2f_hi(u.x), b2f_lo(u.y), b2f_hi(u.y),
                b2f_lo(u.z), b2f_hi(u.z), b2f_lo(u.w), b2f_hi(u.w)};
  u16 r[8];
  float os = 0.f, oq = 0.f;
#pragma unroll
  for (int j = 0; j < 8; j++) {
    float gg = ldx(g, lane * 8 + j, flag);
    float bb = ldx(b, lane * 8 + j, flag);
    r[j] = f2b((f[j] - m) * rvv * gg + bb);
    float hv = b2f(r[j]);
    os += hv;
    oq = fmaf(hv, hv, oq);
  }
  uint4 pr;
  pr.x = (u32)r[0] | ((u32)r[1] << 16);
  pr.y = (u32)r[2] | ((u32)r[3] << 16);
  pr.z = (u32)r[4] | ((u32)r[5] << 16);
  pr.w = (u32)r[6] | ((u32)r[7] << 16);
  *(uint4*)(out + (size_t)row * DD + lane * 8) = pr;
  // output stats (for layer-0 LN1 consumer)
#pragma unroll
  for (int o = 1; o < 64; o <<= 1) {
    os += __shfl_xor(os, o, 64);
    oq += __shfl_xor(oq, o, 64);
  }
  if (lane == 0) {
    float mo = os * (1.f / DD);
    float vo = oq * (1.f / DD) - mo * mo;
    muv[row] = mo;
    rinvv[row] = 1.0f / sqrtf(vo + 1e-5f);
  }
}

// ---------------- Performer KV via MFMA -> transposed output ----------------
// T14-lite: next iteration's V tile prefetched into 4 VGPRs during compute,
// so the V stage after the barrier is register-sourced (no exposed HBM latency).
__global__ __launch_bounds__(256) void kv_kernel_mfma(
    const u16* __restrict__ Kb, const u16* __restrict__ Vb,
    const u16* __restrict__ omt, u16* __restrict__ KVT_g) {
  int bh = blockIdx.x; int b = bh >> 3, h = bh & 7;
  int tid = threadIdx.x;
  int wid = tid >> 6, lane = tid & 63;
  int quad = lane >> 4, cl = lane & 15;
  __shared__ u16 VT[80 * 40];
  __shared__ u16 KfT[256 * 40];

  short8 omB[4][2];
#pragma unroll
  for (int nt = 0; nt < 4; nt++)
#pragma unroll
    for (int ks = 0; ks < 2; ks++)
      omB[nt][ks] = *(const short8*)(omt + (size_t)(wid * 64 + nt * 16 + cl) * 64
                                         + ks * 32 + quad * 8);
  for (int e = tid; e < 512; e += 256)
    VT[(64 + (e >> 5)) * 40 + (e & 31)] = ((e >> 5) == 0) ? (u16)0x3F80 : (u16)0;

  // prefetch V tile for l0=0
  u32 vreg[4];
#pragma unroll
  for (int i = 0; i < 4; i++) {
    int idx = tid + i * 256;
    int rr = idx >> 5, pp = idx & 31;
    vreg[i] = *(const u32*)(Vb + ((size_t)(b * LL + rr)) * DD + h * DHH + pp * 2);
  }

  f32x4 acc2[4][5] = {};

  for (int l0 = 0; l0 < LL; l0 += 32) {
    __syncthreads();   // WAR: prev iter's acc2 reads of VT complete
#pragma unroll
    for (int i = 0; i < 4; i++) {
      int idx = tid + i * 256;
      int rr = idx >> 5, pp = idx & 31;
      u32 uv = vreg[i];
      VT[(pp * 2) * 40 + rr] = (u16)(uv & 0xFFFF);
      VT[(pp * 2 + 1) * 40 + rr] = (u16)(uv >> 16);
    }
    if (l0 + 32 < LL) {   // issue next tile's V loads; consumed next iteration
#pragma unroll
      for (int i = 0; i < 4; i++) {
        int idx = tid + i * 256;
        int rr = idx >> 5, pp = idx & 31;
        vreg[i] = *(const u32*)(Vb + ((size_t)(b * LL + l0 + 32 + rr)) * DD
                                 + h * DHH + pp * 2);
      }
    }
    short8 aK[2][2];
    float nsk[2];
#pragma unroll
    for (int mt = 0; mt < 2; mt++) {
      const u16* ksrc = Kb + ((size_t)(b * LL + l0 + mt * 16 + cl)) * DD + h * DHH;
#pragma unroll
      for (int ks = 0; ks < 2; ks++)
        aK[mt][ks] = *(const short8*)(ksrc + ks * 32 + quad * 8);
      float q = 0.f;
#pragma unroll
      for (int ks = 0; ks < 2; ks++)
#pragma unroll
        for (int j = 0; j < 8; j++) {
          float f = b2f((u16)aK[mt][ks][j]);
          q = fmaf(f, f, q);
        }
      q += __shfl_xor(q, 16, 64);
      q += __shfl_xor(q, 32, 64);
      nsk[mt] = 0.0625f * q;
    }
    f32x4 acc1[2][4] = {};
#pragma unroll
    for (int ks = 0; ks < 2; ks++)
#pragma unroll
      for (int mt = 0; mt < 2; mt++)
#pragma unroll
        for (int nt = 0; nt < 4; nt++)
          acc1[mt][nt] = __builtin_amdgcn_mfma_f32_16x16x32_bf16(
              aK[mt][ks], omB[nt][ks], acc1[mt][nt], 0, 0, 0);
#pragma unroll
    for (int mt = 0; mt < 2; mt++) {
      f32x4 nsv;
#pragma unroll
      for (int r = 0; r < 4; r++) nsv[r] = __shfl(nsk[mt], quad * 4 + r, 64);
#pragma unroll
      for (int nt = 0; nt < 4; nt++) {
        int m = wid * 64 + nt * 16 + cl;
        u16 kf16[4];
#pragma unroll
        for (int r = 0; r < 4; r++)
          kf16[r] = f2b(__expf(acc1[mt][nt][r] - nsv[r]) * 0.0625f);
        uint2 pk;
        pk.x = (u32)kf16[0] | ((u32)kf16[1] << 16);
        pk.y = (u32)kf16[2] | ((u32)kf16[3] << 16);
        *(uint2*)(&KfT[m * 40 + mt * 16 + quad * 4]) = pk;
      }
    }
    __syncthreads();
    short8 aF[4], bV[5];
#pragma unroll
    for (int mt2 = 0; mt2 < 4; mt2++)
      aF[mt2] = *(const short8*)(&KfT[(wid * 64 + mt2 * 16 + cl) * 40 + quad * 8]);
#pragma unroll
    for (int nt2 = 0; nt2 < 5; nt2++)
      bV[nt2] = *(const short8*)(&VT[(nt2 * 16 + cl) * 40 + quad * 8]);
#pragma unroll
    for (int mt2 = 0; mt2 < 4; mt2++)
#pragma unroll
      for (int nt2 = 0; nt2 < 5; nt2++)
        acc2[mt2][nt2] = __builtin_amdgcn_mfma_f32_16x16x32_bf16(
            aF[mt2], bV[nt2], acc2[mt2][nt2], 0, 0, 0);
  }
  u16* base = KVT_g + (size_t)bh * 80 * 256;
#pragma unroll
  for (int mt2 = 0; mt2 < 4; mt2++) {
    int m0 = wid * 64 + mt2 * 16 + quad * 4;
#pragma unroll
    for (int nt2 = 0; nt2 < 4; nt2++) {
      u16 w[4];
#pragma unroll
      for (int r = 0; r < 4; r++) w[r] = f2b(acc2[mt2][nt2][r]);
      uint2 pk;
      pk.x = (u32)w[0] | ((u32)w[1] << 16);
      pk.y = (u32)w[2] | ((u32)w[3] << 16);
      *(uint2*)(&base[(size_t)(nt2 * 16 + cl) * 256 + m0]) = pk;
    }
    if (cl == 0) {
      u16 w[4];
#pragma unroll
      for (int r = 0; r < 4; r++) w[r] = f2b(acc2[mt2][4][r]);
      uint2 pk;
      pk.x = (u32)w[0] | ((u32)w[1] << 16);
      pk.y = (u32)w[2] | ((u32)w[3] << 16);
      *(uint2*)(&base[(size_t)64 * 256 + m0]) = pk;
    }
  }
}

// ---------------- Performer out via MFMA ----------------
__global__ __launch_bounds__(256) void attn_out_mfma(
    u16* __restrict__ Qb, const u16* __restrict__ KVT_g,
    const u16* __restrict__ omt) {
  int bh = blockIdx.x; int b = bh >> 3, h = bh & 7;
  int chunk = blockIdx.y;
  int tid = threadIdx.x;
  int wid = tid >> 6, lane = tid & 63;
  int quad = lane >> 4, cl = lane & 15;
  __shared__ u16 smem[64 * 264 + 80 * 264];
  u16* Qf = smem;
  u16* KVT = smem + 64 * 264;

  const u16* kvsrc = KVT_g + (size_t)bh * 80 * 256;
#pragma unroll
  for (int i = 0; i < 9; i++) {
    int idx = tid + i * 256;
    if (idx < 2080) {
      int row = idx >> 5, c8 = (idx & 31) * 8;
      *(uint4*)(&KVT[row * 264 + c8]) = *(const uint4*)(kvsrc + (size_t)row * 256 + c8);
    }
  }

  short8 omB[4][2];
#pragma unroll
  for (int nt = 0; nt < 4; nt++)
#pragma unroll
    for (int ks = 0; ks < 2; ks++)
      omB[nt][ks] = *(const short8*)(omt + (size_t)(wid * 64 + nt * 16 + cl) * 64
                                         + ks * 32 + quad * 8);

  int t0 = chunk * 64;
  short8 aQ[4][2];
  float nss[4];
#pragma unroll
  for (int mt = 0; mt < 4; mt++) {
    int tglob = t0 + mt * 16 + cl;
    int trow = tglob < LL ? tglob : LL - 1;
    const u16* qsrc = Qb + ((size_t)(b * LL + trow)) * DD + h * DHH;
#pragma unroll
    for (int ks = 0; ks < 2; ks++)
      aQ[mt][ks] = *(const short8*)(qsrc + ks * 32 + quad * 8);
    float q = 0.f;
#pragma unroll
    for (int ks = 0; ks < 2; ks++)
#pragma unroll
      for (int j = 0; j < 8; j++) {
        float f = b2f((u16)aQ[mt][ks][j]);
        q = fmaf(f, f, q);
      }
    q += __shfl_xor(q, 16, 64);
    q += __shfl_xor(q, 32, 64);
    nss[mt] = 0.0625f * q;
  }

  f32x4 acc1[4][4] = {};
#pragma unroll
  for (int ks = 0; ks < 2; ks++)
#pragma unroll
    for (int mt = 0; mt < 4; mt++)
#pragma unroll
      for (int nt = 0; nt < 4; nt++)
        acc1[mt][nt] = __builtin_amdgcn_mfma_f32_16x16x32_bf16(
            omB[nt][ks], aQ[mt][ks], acc1[mt][nt], 0, 0, 0);
#pragma unroll
  for (int mt = 0; mt < 4; mt++) {
#pragma unroll
    for (int nt = 0; nt < 4; nt++) {
      u16 w[4];
#pragma unroll
      for (int r = 0; r < 4; r++)
        w[r] = f2b(__expf(acc1[mt][nt][r] - nss[mt]) * 0.0625f);
      uint2 pk;
      pk.x = (u32)w[0] | ((u32)w[1] << 16);
      pk.y = (u32)w[2] | ((u32)w[3] << 16);
      *(uint2*)(&Qf[(mt * 16 + cl) * 264 + wid * 64 + nt * 16 + quad * 4]) = pk;
    }
  }
  __syncthreads();
  f32x4 acc2[5] = {};
#pragma unroll
  for (int ks2 = 0; ks2 < 8; ks2++) {
    short8 aF = *(const short8*)(&Qf[(wid * 16 + cl) * 264 + ks2 * 32 + quad * 8]);
#pragma unroll
    for (int nt2 = 0; nt2 < 5; nt2++) {
      short8 bK = *(const short8*)(&KVT[(nt2 * 16 + cl) * 264 + ks2 * 32 + quad * 8]);
      acc2[nt2] = __builtin_amdgcn_mfma_f32_16x16x32_bf16(bK, aF, acc2[nt2], 0, 0, 0);
    }
  }
  float nval = __shfl(acc2[4][0], cl, 64);
  float inv = 1.0f / fmaxf(nval, 1e-6f);
  int tglob = t0 + wid * 16 + cl;
  if (tglob < LL) {
    u16* dst = Qb + ((size_t)(b * LL + tglob)) * DD + h * DHH;
#pragma unroll
    for (int nt2 = 0; nt2 < 4; nt2++) {
      u16 w[4];
#pragma unroll
      for (int r = 0; r < 4; r++) w[r] = f2b(acc2[nt2][r] * inv);
      uint2 pk;
      pk.x = (u32)w[0] | ((u32)w[1] << 16);
      pk.y = (u32)w[2] | ((u32)w[3] << 16);
      *(uint2*)(dst + nt2 * 16 + quad * 4) = pk;
    }
  }
}

// ---------------- pooling ----------------
__global__ __launch_bounds__(256) void softmax_kernel(const float* __restrict__ sc,
    float* __restrict__ alpha) {
  __shared__ float sm[4];
  int b = blockIdx.x, tid = threadIdx.x;
  float mx = -1e30f;
  for (int i = tid; i < LL; i += 256) mx = fmaxf(mx, sc[b * LL + i]);
#pragma unroll
  for (int o = 32; o; o >>= 1) mx = fmaxf(mx, __shfl_down(mx, o, 64));
  if ((tid & 63) == 0) sm[tid >> 6] = mx;
  __syncthreads();
  mx = fmaxf(fmaxf(sm[0], sm[1]), fmaxf(sm[2], sm[3]));
  float s = 0.f;
  for (int i = tid; i < LL; i += 256) {
    float e = expf(sc[b * LL + i] - mx);
    alpha[b * LL + i] = e;
    s += e;
  }
  __syncthreads();
#pragma unroll
  for (int o = 32; o; o >>= 1) s += __shfl_down(s, o, 64);
  if ((tid & 63) == 0) sm[tid >> 6] = s;
  __syncthreads();
  float invs = 1.f / (sm[0] + sm[1] + sm[2] + sm[3]);
  for (int i = tid; i < LL; i += 256) alpha[b * LL + i] *= invs;
}

// attentive-pool partials: grid (BB, 8), each block covers 100 tokens
__global__ __launch_bounds__(512) void pool_part_kernel(const u16* __restrict__ h,
    const float* __restrict__ alpha, float* __restrict__ pmu, float* __restrict__ pm2) {
  int b = blockIdx.x, seg = blockIdx.y, d = threadIdx.x;
  const u16* hb = h + (size_t)b * LL * DD + (size_t)seg * 100 * DD + d;
  const float* ab = alpha + b * LL + seg * 100;
  float mu = 0.f, m2 = 0.f;
  for (int l = 0; l < 100; l++) {
    float a = ab[l], v = b2f(hb[(size_t)l * DD]);
    mu = fmaf(a, v, mu);
    m2 = fmaf(a * v, v, m2);
  }
  pmu[((size_t)seg * BB + b) * DD + d] = mu;
  pm2[((size_t)seg * BB + b) * DD + d] = m2;
}

__global__ __launch_bounds__(512) void pool_reduce_kernel(const float* __restrict__ pmu,
    const float* __restrict__ pm2, float* __restrict__ feat) {
  int b = blockIdx.x, d = threadIdx.x;
  float mu = 0.f, m2 = 0.f;
#pragma unroll
  for (int s = 0; s < 8; s++) {
    mu += pmu[((size_t)s * BB + b) * DD + d];
    m2 += pm2[((size_t)s * BB + b) * DD + d];
  }
  feat[b * 2 * DD + d] = mu;
  feat[b * 2 * DD + DD + d] = sqrtf(fmaxf(m2 - mu * mu, 1e-8f));
}

__global__ __launch_bounds__(320) void head_kernel(const float* __restrict__ feat,
    const void* __restrict__ hw, const void* __restrict__ hb, void* out,
    const u32* __restrict__ dflag) {
  int flag = (int)dflag[0];
  int b = blockIdx.x;
  int t = threadIdx.x;
  int n = t >> 5, j0 = t & 31;
  float p = 0.f;
  for (int j = j0; j < 2 * DD; j += 32)
    p = fmaf(feat[b * 2 * DD + j], ldx(hw, (size_t)j * NCLS + n, flag), p);
#pragma unroll
  for (int o = 16; o; o >>= 1) p += __shfl_down(p, o, 32);
  if (j0 == 0) {
    float v = p + ldx(hb, n, flag);
    if (flag) ((u16*)out)[b * NCLS + n] = f2b(v);
    else ((float*)out)[b * NCLS + n] = v;
  }
}

// ---------------- host launch ----------------
extern "C" void kernel_launch(void* const* d_in, const int* in_sizes, int n_in,
                              void* d_out, int out_size, void* d_ws, size_t ws_size,
                              hipStream_t stream) {
  char* ws = (char*)d_ws;
  size_t off = 0;
  auto alloc = [&](size_t bytes) -> char* {
    char* p = ws + off;
    off += (bytes + 255) & ~(size_t)255;
    return p;
  };
  u16* hbuf = (u16*)alloc((size_t)BL * DD * 2);
  u16* buf1 = (u16*)alloc((size_t)BL * DD * 2);
  u16* buf2 = (u16*)alloc((size_t)BL * DD * 2);
  u16* KVT_g = (u16*)alloc((size_t)BB * HH * 80 * 256 * 2);
  float* muv = (float*)alloc((size_t)BL * 4);
  float* rinvv = (float*)alloc((size_t)BL * 4);
  float* scores = (float*)alloc((size_t)BL * 4);
  float* alpha = (float*)alloc((size_t)BL * 4);
  float* feat = (float*)alloc((size_t)BB * 2 * DD * 4);
  float* uvec = (float*)alloc((size_t)NUC * 4);
  float* cvec = (float*)alloc((size_t)NUC * 4);
  float* pU = (float*)alloc((size_t)8 * NUC * 4);
  float* pC = (float*)alloc((size_t)8 * NUC * 4);
  float* pSum = (float*)alloc((size_t)8 * BL * 4);
  float* pSsq = (float*)alloc((size_t)8 * BL * 4);
  u16* ombT = (u16*)alloc((size_t)NLAYER * MM * DHH * 2);
  u16* wtall = (u16*)alloc((size_t)WT_TOTAL * 2);
  u32* dflag = (u32*)alloc(256);
  size_t off_base = off;
  u16* bufQ = (u16*)alloc((size_t)BL * DD * 2);       // fused-QKV Q buffer (ws-gated)
  size_t off_full = off;

  if (ws_size < off_base) {
    sentinel_kernel<<<2, 256, 0, stream>>>((u16*)d_out, out_size);
    return;
  }
  const bool fused = (ws_size >= off_full);

  const void* x       = d_in[0];
  const void* patchW  = d_in[1];
  const void* patchb  = d_in[2];
  const void* patchg  = d_in[3];
  const void* patchbe = d_in[4];
  const void* ln1g    = d_in[5];
  const void* ln1b    = d_in[6];
  const void* qW      = d_in[7];
  const void* kW      = d_in[8];
  const void* vW      = d_in[9];
  const void* oW      = d_in[10];
  const void* ob      = d_in[11];
  const void* omg     = d_in[12];
  const void* ln2g    = d_in[13];
  const void* ln2b    = d_in[14];
  const void* f1W     = d_in[15];
  const void* f1b     = d_in[16];
  const void* f2W     = d_in[17];
  const void* f2b_    = d_in[18];
  const void* poolW1  = d_in[19];
  const void* poolW2  = d_in[20];
  const void* headW   = d_in[21];
  const void* headb   = d_in[22];

  sniff_kernel<<<1, 64, 0, stream>>>((const u32*)patchg, dflag);

  patchify_kernel<<<(BL * KPATCH) / 256, 256, 0, stream>>>(x, buf1, dflag);
  omcvt_kernel<<<(NLAYER * MM * DHH + 255) / 256, 256, 0, stream>>>(omg, ombT, dflag);
  // ALL weight transposes + LN-fold partials in one dispatch
  megawt_kernel<<<1072, 256, 0, stream>>>(patchW, qW, kW, vW, oW, f1W, f2W, poolW1,
                                          ln1g, ln1b, ln2g, ln2b, wtall, pU, pC, dflag);
  ucr_kernel<<<NUC / 256, 256, 0, stream>>>(pU, pC, uvec, cvec, NUC);

  // patch GEMM (+stats of its output) -> ln_apply (stats-in from pS, stats-out muv/rinvv)
  mgemm<0, true, false, 0, false, true, false><<<dim3(4, 200), 256, 0, stream>>>(
      buf1, wtall + WT_PATCH, patchb, 0, nullptr, nullptr, nullptr, nullptr,
      nullptr, buf2, nullptr, nullptr, pSum, pSsq, KPATCH, DD, dflag);
  ln_apply_kernel<<<BL / 4, 256, 0, stream>>>(buf2, pSum, pSsq, patchg, patchbe,
                                              hbuf, muv, rinvv, dflag);

  for (int l = 0; l < NLAYER; l++) {
    size_t oD = (size_t)l * DD;
    size_t oF = (size_t)l * FF;
    const u16* omtl = ombT + (size_t)l * MM * DHH;
    const u16* qkvT = wtall + (l == 0 ? WT_QKV0 : WT_QKV1);
    const u16* oWT  = wtall + (l == 0 ? WT_OW0 : WT_OW1);
    const u16* f1T  = wtall + (l == 0 ? WT_F10 : WT_F11);
    const u16* f2T  = wtall + (l == 0 ? WT_F20 : WT_F21);
    const float* uq = uvec + (l == 0 ? 0 : 2560);
    const float* cq = cvec + (l == 0 ? 0 : 2560);
    const float* uf = uvec + (l == 0 ? 1536 : 4096);
    const float* cf = cvec + (l == 0 ? 1536 : 4096);

    u16* qb;
    if (fused) {
      if (l == 0)
        mgemm<0, false, false, 1, true, false, false><<<dim3(12, 200), 256, 0, stream>>>(
            hbuf, qkvT, nullptr, 0, muv, rinvv, uq, cq, nullptr,
            buf1, buf2, bufQ, nullptr, nullptr, DD, 3 * DD, dflag);
      else
        mgemm<0, false, false, 2, true, false, false><<<dim3(12, 200), 256, 0, stream>>>(
            hbuf, qkvT, nullptr, 0, pSum, pSsq, uq, cq, nullptr,
            buf1, buf2, bufQ, nullptr, nullptr, DD, 3 * DD, dflag);
      kv_kernel_mfma<<<BB * HH, 256, 0, stream>>>(buf1, buf2, omtl, KVT_g);
      qb = bufQ;
    } else {
      // non-fused: K, V, kv, then Q into buf1
      if (l == 0) {
        mgemm<0, false, false, 1, false, false, false><<<dim3(4, 200), 256, 0, stream>>>(
            hbuf, qkvT, nullptr, 0, muv, rinvv, uq, cq, nullptr,
            buf1, nullptr, nullptr, nullptr, nullptr, DD, DD, dflag);
        mgemm<0, false, false, 1, false, false, false><<<dim3(4, 200), 256, 0, stream>>>(
            hbuf, qkvT + 262144, nullptr, 0, muv, rinvv, uq + 512, cq + 512, nullptr,
            buf2, nullptr, nullptr, nullptr, nullptr, DD, DD, dflag);
      } else {
        mgemm<0, false, false, 2, false, false, false><<<dim3(4, 200), 256, 0, stream>>>(
            hbuf, qkvT, nullptr, 0, pSum, pSsq, uq, cq, nullptr,
            buf1, nullptr, nullptr, nullptr, nullptr, DD, DD, dflag);
        mgemm<0, false, false, 2, false, false, false><<<dim3(4, 200), 256, 0, stream>>>(
            hbuf, qkvT + 262144, nullptr, 0, pSum, pSsq, uq + 512, cq + 512, nullptr,
            buf2, nullptr, nullptr, nullptr, nullptr, DD, DD, dflag);
      }
      kv_kernel_mfma<<<BB * HH, 256, 0, stream>>>(buf1, buf2, omtl, KVT_g);
      if (l == 0)
        mgemm<0, false, false, 1, false, false, false><<<dim3(4, 200), 256, 0, stream>>>(
            hbuf, qkvT + 524288, nullptr, 0, muv, rinvv, uq + 1024, cq + 1024, nullptr,
            buf1, nullptr, nullptr, nullptr, nullptr, DD, DD, dflag);
      else
        mgemm<0, false, false, 2, false, false, false><<<dim3(4, 200), 256, 0, stream>>>(
            hbuf, qkvT + 524288, nullptr, 0, pSum, pSsq, uq + 1024, cq + 1024, nullptr,
            buf1, nullptr, nullptr, nullptr, nullptr, DD, DD, dflag);
      qb = buf1;
    }
    attn_out_mfma<<<dim3(BB * HH, 13), 256, 0, stream>>>(qb, KVT_g, omtl);
    // h += attn @ oW + ob  (+ stats of new h for LN2)
    mgemm<0, true, true, 0, false, true, false><<<dim3(4, 200), 256, 0, stream>>>(
        qb, oWT, ob, oD, nullptr, nullptr, nullptr, nullptr,
        hbuf, hbuf, nullptr, nullptr, pSum, pSsq, DD, DD, dflag);
    // FFN: f1 (LN2 folded via pS) -> f2 (+res; stats only if feeding next layer's LN1)
    mgemm<1, true, false, 2, false, false, false><<<dim3(8, 200), 256, 0, stream>>>(
        hbuf, f1T, f1b, oF, pSum, pSsq, uf, cf, nullptr,
        buf1, nullptr, nullptr, nullptr, nullptr, DD, FF, dflag);
    if (l == 0)
      mgemm<0, true, true, 0, false, true, false><<<dim3(4, 200), 256, 0, stream>>>(
          buf1, f2T, f2b_, oD, nullptr, nullptr, nullptr, nullptr,
          hbuf, hbuf, nullptr, nullptr, pSum, pSsq, FF, DD, dflag);
    else
      mgemm<0, true, true, 0, false, false, false><<<dim3(4, 200), 256, 0, stream>>>(
          buf1, f2T, f2b_, oD, nullptr, nullptr, nullptr, nullptr,
          hbuf, hbuf, nullptr, nullptr, nullptr, nullptr, FF, DD, dflag);
  }

  // pool GEMM with fused tanh + score (dot with poolW2) -> scores; no tile store
  mgemm<2, false, false, 0, false, false, true><<<dim3(1, 200), 256, 0, stream>>>(
      hbuf, wtall + WT_POOL, poolW2, 0, nullptr, nullptr, nullptr, nullptr,
      nullptr, nullptr, nullptr, nullptr, scores, nullptr, DD, HIDP, dflag);
  softmax_kernel<<<BB, 256, 0, stream>>>(scores, alpha);
  // attentive-stats pooling: partials (reuse pSum/pSsq, free by now) + reduce
  pool_part_kernel<<<dim3(BB, 8), 512, 0, stream>>>(hbuf, alpha, pSum, pSsq);
  pool_reduce_kernel<<<BB, 512, 0, stream>>>(pSum, pSsq, feat);
  head_kernel<<<BB, 320, 0, stream>>>(feat, headW, headb, d_out, dflag);
}

// Round 10
// 813.099 us; speedup vs baseline: 1.2149x; 1.2149x over previous
//
#include <hip/hip_runtime.h>
#include <math.h>

// ---- problem dims ----
#define BB 32
#define CC 8
#define TT 20000
#define PP 25
#define LL 800          // T/P
#define CP 200          // C*P
#define DD 512
#define HH 8
#define MM 256
#define NLAYER 2
#define DHH 64
#define FF 1024
#define NCLS 10
#define HIDP 128
#define BL (BB*LL)      // 25600
#define KPATCH 256      // C*P=200 zero-padded to 256

// wtall element offsets (all transposed weights, bf16)
#define WT_PATCH 0
#define WT_QKV0  131072
#define WT_OW0   917504
#define WT_F10   1179648
#define WT_F20   1703936
#define WT_QKV1  2228224
#define WT_OW1   3014656
#define WT_F11   3276800
#define WT_F21   3801088
#define WT_POOL  4325376
#define WT_TOTAL 4390912
#define NUC 5120        // packed uvec/cvec width: qkv0|f1_0|qkv1|f1_1

typedef unsigned short u16;
typedef unsigned int u32;
typedef __attribute__((ext_vector_type(8))) short short8;
typedef __attribute__((ext_vector_type(4))) float f32x4;

// bf16 <-> fp32 helpers
__device__ __forceinline__ float b2f(u16 v) { return __uint_as_float(((u32)v) << 16); }
__device__ __forceinline__ float b2f_lo(u32 u) { return __uint_as_float(u << 16); }
__device__ __forceinline__ float b2f_hi(u32 u) { return __uint_as_float(u & 0xFFFF0000u); }
__device__ __forceinline__ u16 f2b(float f) {
  u32 u = __float_as_uint(f);
  u32 r = u + 0x7FFFu + ((u >> 16) & 1u);
  return (u16)(r >> 16);
}
// dual-dtype external read: flag=0 fp32, flag=1 bf16
__device__ __forceinline__ float ldx(const void* p, size_t i, int flag) {
  return flag ? b2f(((const u16*)p)[i]) : ((const float*)p)[i];
}
// async global->LDS, 16B per lane; lds dest = wave-uniform base + lane*16
typedef const __attribute__((address_space(1))) u32 gas_u32;
typedef __attribute__((address_space(3))) u32 las_u32;
__device__ __forceinline__ void gload16(const void* g, void* l) {
  __builtin_amdgcn_global_load_lds((gas_u32*)(size_t)g, (las_u32*)(size_t)l, 16, 0, 0);
}

// ---------------- dtype sniffer: patch_g is all-ones ----------------
__global__ void sniff_kernel(const u32* __restrict__ g, u32* __restrict__ flagp) {
  if (threadIdx.x == 0) flagp[0] = (g[0] == 0x3F800000u) ? 0u : 1u;
}

__global__ void sentinel_kernel(u16* out, int n) {
  int i = blockIdx.x * 256 + threadIdx.x;
  if (i < n) out[i] = f2b(1.0e9f);
}

// ---------------- patchify: x(B,C,T) -> tok(B*L, 256) bf16, cols>=200 zero ----------------
__global__ void patchify_kernel(const void* __restrict__ x, u16* __restrict__ tok,
                                const u32* __restrict__ dflag) {
  int flag = (int)dflag[0];
  int idx = blockIdx.x * 256 + threadIdx.x;
  if (idx >= BL * KPATCH) return;
  int col = idx & (KPATCH - 1), row = idx >> 8;
  if (col >= CP) { tok[idx] = 0; return; }
  int b = row / LL, l = row % LL;
  int c = col / PP, p = col % PP;
  tok[idx] = f2b(ldx(x, ((size_t)b * CC + c) * TT + l * PP + p, flag));
}

// ---------------- omega -> bf16 * 64^-0.25, transposed [l][feat][k] ----------------
__global__ void omcvt_kernel(const void* __restrict__ om, u16* __restrict__ ombT,
                             const u32* __restrict__ dflag) {
  int flag = (int)dflag[0];
  const float inv4 = 0.35355339059327373f;  // 64^-0.25
  int idx = blockIdx.x * 256 + threadIdx.x;
  if (idx >= NLAYER * MM * DHH) return;
  int l = idx >> 14;          // / (MM*DHH)
  int r = idx & (MM * DHH - 1);
  int feat = r >> 6, k = r & 63;
  ombT[idx] = f2b(inv4 * ldx(om, (size_t)l * DHH * MM + (size_t)k * MM + feat, flag));
}

// ---------------- mega weight-transpose: ALL matrices in one dispatch ----------------
// Wt[n][k] = g[k]*W[woff + k*N + n]; pU[ky][ucoff+n] = sum_k g_k W_kn (stride NUC).
struct Seg { int t0, wsel, gsel, woff, goff, wtoff, ucoff, K, N, Kp; };
__constant__ Seg g_segs[14] = {
  {   0, 0, -1,      0,   0, WT_PATCH,          -1,  200,  512,  256},
  {  32, 2,  0,      0,   0, WT_QKV0,             0,  512,  512,  512},
  {  96, 3,  0,      0,   0, WT_QKV0 + 262144,  512,  512,  512,  512},
  { 160, 1,  0,      0,   0, WT_QKV0 + 524288, 1024,  512,  512,  512},
  { 224, 4, -1,      0,   0, WT_OW0,            -1,  512,  512,  512},
  { 288, 5,  1,      0,   0, WT_F10,           1536,  512, 1024,  512},
  { 416, 6, -1,      0,   0, WT_F20,            -1, 1024,  512, 1024},
  { 544, 2,  0, 262144, 512, WT_QKV1,          2560,  512,  512,  512},
  { 608, 3,  0, 262144, 512, WT_QKV1 + 262144, 3072,  512,  512,  512},
  { 672, 1,  0, 262144, 512, WT_QKV1 + 524288, 3584,  512,  512,  512},
  { 736, 4, -1, 262144,   0, WT_OW1,            -1,  512,  512,  512},
  { 800, 5,  1, 524288, 512, WT_F11,           4096,  512, 1024,  512},
  { 928, 6, -1, 524288,   0, WT_F21,            -1, 1024,  512, 1024},
  {1056, 7, -1,      0,   0, WT_POOL,           -1,  512,  128,  512},
};

__global__ __launch_bounds__(256) void megawt_kernel(
    const void* __restrict__ patchW, const void* __restrict__ qW,
    const void* __restrict__ kW, const void* __restrict__ vW,
    const void* __restrict__ oW, const void* __restrict__ f1W,
    const void* __restrict__ f2W, const void* __restrict__ poolW1,
    const void* __restrict__ ln1g, const void* __restrict__ ln1b,
    const void* __restrict__ ln2g, const void* __restrict__ ln2b,
    u16* __restrict__ wtall, float* __restrict__ pU, float* __restrict__ pC,
    const u32* __restrict__ dflag) {
  int flag = (int)dflag[0];
  int bid = blockIdx.x;
  int si = 0;
#pragma unroll
  for (int i = 1; i < 14; i++) if (bid >= g_segs[i].t0) si = i;
  Seg sg = g_segs[si];
  const void* W = (sg.wsel == 0) ? patchW : (sg.wsel == 1) ? qW : (sg.wsel == 2) ? kW
               : (sg.wsel == 3) ? vW : (sg.wsel == 4) ? oW : (sg.wsel == 5) ? f1W
               : (sg.wsel == 6) ? f2W : poolW1;
  const void* gv = (sg.gsel == 0) ? ln1g : (sg.gsel == 1) ? ln2g : nullptr;
  const void* bv = (sg.gsel == 0) ? ln1b : (sg.gsel == 1) ? ln2b : nullptr;
  int lt = bid - sg.t0;
  int nx = sg.N >> 6;
  int n0 = (lt % nx) * 64, k0 = (lt / nx) * 64;
  bool hasU = sg.ucoff >= 0;

  __shared__ float tile[64][65];
  __shared__ float sU[4][64], sC[4][64];
  int tn = threadIdx.x & 63;
  int tk = threadIdx.x >> 6;
  float su = 0.f, sc = 0.f;
#pragma unroll 4
  for (int i = 0; i < 16; i++) {
    int k = k0 + tk * 16 + i;
    float gw = 0.f;
    if (k < sg.K) {
      float w = ldx(W, (size_t)sg.woff + (size_t)k * sg.N + n0 + tn, flag);
      float g = gv ? ldx(gv, (size_t)sg.goff + k, flag) : 1.0f;
      gw = g * w;
      if (hasU) {
        su += gw;
        sc = fmaf(ldx(bv, (size_t)sg.goff + k, flag), w, sc);
      }
    }
    tile[tk * 16 + i][tn] = gw;
  }
  if (hasU) { sU[tk][tn] = su; sC[tk][tn] = sc; }
  __syncthreads();
  if (hasU && tk == 0) {
    pU[(size_t)(k0 >> 6) * NUC + sg.ucoff + n0 + tn] =
        sU[0][tn] + sU[1][tn] + sU[2][tn] + sU[3][tn];
    pC[(size_t)(k0 >> 6) * NUC + sg.ucoff + n0 + tn] =
        sC[0][tn] + sC[1][tn] + sC[2][tn] + sC[3][tn];
  }
#pragma unroll 4
  for (int i = 0; i < 16; i++) {
    int n = n0 + tk * 16 + i;
    wtall[(size_t)sg.wtoff + (size_t)n * sg.Kp + k0 + tn] = f2b(tile[tn][tk * 16 + i]);
  }
}

// reduce 8 partials -> u,c (N = NUC, one dispatch for everything)
__global__ __launch_bounds__(256) void ucr_kernel(const float* __restrict__ pU,
    const float* __restrict__ pC, float* __restrict__ u, float* __restrict__ c, int N) {
  int n = blockIdx.x * 256 + threadIdx.x;
  if (n >= N) return;
  float su = 0.f, sc = 0.f;
#pragma unroll
  for (int ky = 0; ky < 8; ky++) {
    su += pU[(size_t)ky * N + n];
    sc += pC[(size_t)ky * N + n];
  }
  u[n] = su;
  c[n] = sc;
}

// ---------------- MFMA GEMM: out = act(epi(A @ Wt^T) + bias) [+ res] ----------------
// 128x128 tile, BK=64, 4 waves. XCD-aware block swizzle. LDS C-tile repack store.
// LNE: 0 none; 1 stats from muv/rinvv arrays; 2 stats derived from 8-slot partials.
// STATS: epilogue writes per-row partial sum/sumsq of the ROUNDED stored values.
// SCORE: (pool path, N=128) epilogue computes scores[row] = dot(Cs row, bias[0..127])
//        and skips the global tile store entirely (output consumed only by softmax).
template<int ACT, bool HAS_BIAS, bool HAS_RES, int LNE, bool SPLIT3, bool STATS, bool SCORE>
__global__ __launch_bounds__(256, 4) void mgemm(
    const u16* __restrict__ A, const u16* __restrict__ Wt,
    const void* __restrict__ bias, size_t biasoff,
    const float* __restrict__ stA, const float* __restrict__ stB,
    const float* __restrict__ uvec, const float* __restrict__ cvec,
    const u16* res, u16* out, u16* out2, u16* out3,
    float* __restrict__ oSum, float* __restrict__ oSsq,
    int Kp, int N, const u32* __restrict__ dflag) {
  const int flag = (int)dflag[0];
  alignas(16) __shared__ u16 smem[128 * 128];   // As | Bs during K-loop; C-tile in epilogue
  __shared__ float statL[256];                  // [0..127] mu, [128..255] rinv
  u16* As = smem;
  u16* Bs = smem + 128 * 64;
  int tid = threadIdx.x;
  // XCD-aware swizzle (gridDim.y % 8 == 0 for all call sites)
  int flat = blockIdx.y * gridDim.x + blockIdx.x;
  int xcd = flat & 7;
  int p_ = flat >> 3;
  int gx = gridDim.x;
  int mtile = xcd * (gridDim.y >> 3) + p_ / gx;
  int ntile = p_ % gx;
  int m0 = mtile * 128, n0 = ntile * 128;
  int wid = tid >> 6, lane = tid & 63;
  int wm = (wid >> 1) * 64, wn = (wid & 1) * 64;
  int quad = lane >> 4, cl = lane & 15;

  if (LNE == 1) {
    if (tid < 128) {
      statL[tid] = stA[m0 + tid];
      statL[128 + tid] = stB[m0 + tid];
    }
  } else if (LNE == 2) {
    if (tid < 128) {
      float s = 0.f, q = 0.f;
#pragma unroll
      for (int s8 = 0; s8 < 8; s8++) {
        s += stA[(size_t)s8 * BL + m0 + tid];
        q += stB[(size_t)s8 * BL + m0 + tid];
      }
      float mu = s * (1.f / DD);
      float var = q * (1.f / DD) - mu * mu;
      statL[tid] = mu;
      statL[128 + tid] = 1.0f / sqrtf(var + 1e-5f);
    }
  }

  f32x4 acc[4][4] = {};
  int r_ = tid >> 3, c_ = tid & 7;
  for (int k0 = 0; k0 < Kp; k0 += 64) {
    __syncthreads();
#pragma unroll
    for (int p = 0; p < 4; p++) {
      int row = p * 32 + r_;
      int gc = (c_ ^ (row & 7)) * 8;
      int lbase = ((p * 256 + (tid & ~63)) * 8);
      gload16(A + (size_t)(m0 + row) * Kp + k0 + gc, &As[lbase]);
      gload16(Wt + (size_t)(n0 + row) * Kp + k0 + gc, &Bs[lbase]);
    }
    __syncthreads();
#pragma unroll
    for (int kk = 0; kk < 64; kk += 32) {
      int qb = (kk >> 3) + quad;
      short8 af[4], bf[4];
#pragma unroll
      for (int mt = 0; mt < 4; mt++) {
        int arow = wm + mt * 16 + cl;
        af[mt] = *(const short8*)(&As[(arow * 8 + (qb ^ (cl & 7))) * 8]);
      }
#pragma unroll
      for (int nt = 0; nt < 4; nt++) {
        int brow = wn + nt * 16 + cl;
        bf[nt] = *(const short8*)(&Bs[(brow * 8 + (qb ^ (cl & 7))) * 8]);
      }
#pragma unroll
      for (int mt = 0; mt < 4; mt++)
#pragma unroll
        for (int nt = 0; nt < 4; nt++)
          acc[mt][nt] = __builtin_amdgcn_mfma_f32_16x16x32_bf16(
              af[mt], bf[nt], acc[mt][nt], 0, 0, 0);
    }
  }
  // ---- epilogue: compute final bf16 values into LDS tile ----
  __syncthreads();
  u16* Cs = smem;  // 128 x 128 bf16, row-major
  float sA[4][4] = {}, qA[4][4] = {};
#pragma unroll
  for (int nt = 0; nt < 4; nt++) {
    int tcol = wn + nt * 16 + cl;
    int gcol = n0 + tcol;
    float bvv = HAS_BIAS ? ldx(bias, biasoff + gcol, flag) : 0.f;
    float uv_ = 0.f, cv_ = 0.f;
    if (LNE) { uv_ = uvec[gcol]; cv_ = cvec[gcol]; }
#pragma unroll
    for (int mt = 0; mt < 4; mt++) {
#pragma unroll
      for (int r = 0; r < 4; r++) {
        int trow = wm + mt * 16 + quad * 4 + r;
        int grow = m0 + trow;
        float v = acc[mt][nt][r];
        if (LNE) {
          float rv_ = statL[128 + trow];
          v = rv_ * v - rv_ * statL[trow] * uv_ + cv_;
        }
        v += bvv;
        if (ACT == 1) v = 0.5f * v * (1.0f + erff(v * 0.7071067811865476f));
        else if (ACT == 2) v = tanhf(v);
        if (HAS_RES) v += b2f(res[(size_t)grow * N + gcol]);
        u16 wv = f2b(v);
        Cs[trow * 128 + tcol] = wv;
        if (STATS) {
          float vr = b2f(wv);
          sA[mt][r] += vr;
          qA[mt][r] += vr * vr;
        }
      }
    }
  }
  if (STATS) {
#pragma unroll
    for (int mt = 0; mt < 4; mt++)
#pragma unroll
      for (int r = 0; r < 4; r++) {
        float s = sA[mt][r], q = qA[mt][r];
        s += __shfl_xor(s, 1, 64); s += __shfl_xor(s, 2, 64);
        s += __shfl_xor(s, 4, 64); s += __shfl_xor(s, 8, 64);
        q += __shfl_xor(q, 1, 64); q += __shfl_xor(q, 2, 64);
        q += __shfl_xor(q, 4, 64); q += __shfl_xor(q, 8, 64);
        if (cl == 0) {
          int grow = m0 + wm + mt * 16 + quad * 4 + r;
          int slot = ntile * 2 + (wid & 1);
          oSum[(size_t)slot * BL + grow] = s;
          oSsq[(size_t)slot * BL + grow] = q;
        }
      }
  }
  __syncthreads();
  if (SCORE) {
    // pool path: N==128 so this block holds full rows; scores[grow] = Cs row . w2
    // column order staggered by row to avoid same-bank LDS reads across lanes.
    int row = tid >> 1, half = tid & 1;
    float p = 0.f;
#pragma unroll
    for (int j = 0; j < 64; j++) {
      int col = (half << 6) | ((j + row) & 63);
      p += b2f(Cs[row * 128 + col]) * ldx(bias, col, flag);
    }
    p += __shfl_xor(p, 1, 64);
    if (half == 0) oSum[m0 + row] = p;
  } else {
    // ---- coalesced store: each wave writes 4 rows x 256B contiguous per instr ----
    u16* dstbuf;
    int colbase, stride;
    if (SPLIT3) {
      int sel = n0 >> 9;
      dstbuf = (sel == 0) ? out : (sel == 1) ? out2 : out3;
      colbase = n0 & 511;
      stride = 512;
    } else {
      dstbuf = out;
      colbase = n0;
      stride = N;
    }
    int c8 = (tid & 15) * 8, rb = tid >> 4;
#pragma unroll
    for (int i = 0; i < 8; i++) {
      int trow = i * 16 + rb;
      uint4 vv = *(const uint4*)(&Cs[trow * 128 + c8]);
      *(uint4*)(&dstbuf[(size_t)(m0 + trow) * stride + colbase + c8]) = vv;
    }
  }
}

// ---------------- LN apply (patch LN): stats-in from pS partials, stats-out of h ----------------
__global__ __launch_bounds__(256) void ln_apply_kernel(const u16* __restrict__ x,
    const float* __restrict__ pSum, const float* __restrict__ pSsq,
    const void* __restrict__ g, const void* __restrict__ b, u16* __restrict__ out,
    float* __restrict__ muv, float* __restrict__ rinvv,
    const u32* __restrict__ dflag) {
  int flag = (int)dflag[0];
  int row = blockIdx.x * 4 + (threadIdx.x >> 6);
  int lane = threadIdx.x & 63;
  // input stats from 8 partial slots (broadcast loads)
  float s = 0.f, q = 0.f;
#pragma unroll
  for (int s8 = 0; s8 < 8; s8++) {
    s += pSum[(size_t)s8 * BL + row];
    q += pSsq[(size_t)s8 * BL + row];
  }
  float m = s * (1.f / DD);
  float var = q * (1.f / DD) - m * m;
  float rvv = 1.0f / sqrtf(var + 1e-5f);

  const u16* xr = x + (size_t)row * DD + lane * 8;
  uint4 u = *(const uint4*)xr;
  float f[8] = {b2f_lo(u.x), b2f_hi(u.x), b2f_lo(u.y), b2f_hi(u.y),
                b2f_lo(u.z), b2f_hi(u.z), b2f_lo(u.w), b2f_hi(u.w)};
  u16 r[8];
  float os = 0.f, oq = 0.f;
#pragma unroll
  for (int j = 0; j < 8; j++) {
    float gg = ldx(g, lane * 8 + j, flag);
    float bb = ldx(b, lane * 8 + j, flag);
    r[j] = f2b((f[j] - m) * rvv * gg + bb);
    float hv = b2f(r[j]);
    os += hv;
    oq = fmaf(hv, hv, oq);
  }
  uint4 pr;
  pr.x = (u32)r[0] | ((u32)r[1] << 16);
  pr.y = (u32)r[2] | ((u32)r[3] << 16);
  pr.z = (u32)r[4] | ((u32)r[5] << 16);
  pr.w = (u32)r[6] | ((u32)r[7] << 16);
  *(uint4*)(out + (size_t)row * DD + lane * 8) = pr;
  // output stats (for layer-0 LN1 consumer)
#pragma unroll
  for (int o = 1; o < 64; o <<= 1) {
    os += __shfl_xor(os, o, 64);
    oq += __shfl_xor(oq, o, 64);
  }
  if (lane == 0) {
    float mo = os * (1.f / DD);
    float vo = oq * (1.f / DD) - mo * mo;
    muv[row] = mo;
    rinvv[row] = 1.0f / sqrtf(vo + 1e-5f);
  }
}

// ---------------- Performer KV via MFMA -> transposed output ----------------
// 8-wave version: two wave-groups (g=wid>>2), each handling a 32-token subtile per
// iteration (64 tokens/iter, 13 iters). Private VT/KfT per group (KfT same-wave).
// V tiles prefetched into regs (T14-lite). Final: group-1 acc2 partials added into
// group-0 via LDS staging (4 chunks), then group 0 stores KVT_g.
__global__ __launch_bounds__(512) void kv_kernel_mfma(
    const u16* __restrict__ Kb, const u16* __restrict__ Vb,
    const u16* __restrict__ omt, u16* __restrict__ KVT_g) {
  int bh = blockIdx.x; int b = bh >> 3, h = bh & 7;
  int tid = threadIdx.x;
  int wid = tid >> 6;          // 0..7
  int g = wid >> 2;            // wave group 0/1
  int w4 = wid & 3;            // feature wave 0..3
  int lane = tid & 63;
  int quad = lane >> 4, cl = lane & 15;
  alignas(16) __shared__ u16 VT[2][80 * 40];
  alignas(16) __shared__ u16 KfT[2][256 * 40];

  short8 omB[4][2];
#pragma unroll
  for (int nt = 0; nt < 4; nt++)
#pragma unroll
    for (int ks = 0; ks < 2; ks++)
      omB[nt][ks] = *(const short8*)(omt + (size_t)(w4 * 64 + nt * 16 + cl) * 64
                                         + ks * 32 + quad * 8);
  // identity rows (64..79) for both buffers: row 64 = ones (KV row-sum trick)
  for (int e = tid; e < 1024; e += 512) {
    int gg = e >> 9, r = (e >> 5) & 15, c = e & 31;
    VT[gg][(64 + r) * 40 + c] = (r == 0) ? (u16)0x3F80 : (u16)0;
  }

  // prefetch V rows 0..63
  u32 vreg[4];
#pragma unroll
  for (int i = 0; i < 4; i++) {
    int idx = tid + i * 512;
    int rr = idx >> 5, pp = idx & 31;
    vreg[i] = *(const u32*)(Vb + ((size_t)(b * LL + rr)) * DD + h * DHH + pp * 2);
  }

  f32x4 acc2[4][5] = {};

  for (int l0 = 0; l0 < LL; l0 += 64) {
    __syncthreads();   // WAR: prev iter's acc2 reads of VT complete
#pragma unroll
    for (int i = 0; i < 4; i++) {
      int idx = tid + i * 512;
      int rr = idx >> 5, pp = idx & 31;
      u32 uv = vreg[i];
      u16* vt = &VT[rr >> 5][0];
      int rl = rr & 31;
      vt[(pp * 2) * 40 + rl] = (u16)(uv & 0xFFFF);
      vt[(pp * 2 + 1) * 40 + rl] = (u16)(uv >> 16);
    }
    if (l0 + 64 < LL) {   // issue next 64 rows' V loads (guard tail rows)
#pragma unroll
      for (int i = 0; i < 4; i++) {
        int idx = tid + i * 512;
        int rr = idx >> 5, pp = idx & 31;
        int row = l0 + 64 + rr;
        if (row < LL)
          vreg[i] = *(const u32*)(Vb + ((size_t)(b * LL + row)) * DD + h * DHH + pp * 2);
      }
    }
    int myl0 = l0 + g * 32;
    bool act = myl0 < LL;   // wave-uniform
    if (act) {
      short8 aK[2][2];
      float nsk[2];
#pragma unroll
      for (int mt = 0; mt < 2; mt++) {
        const u16* ksrc = Kb + ((size_t)(b * LL + myl0 + mt * 16 + cl)) * DD + h * DHH;
#pragma unroll
        for (int ks = 0; ks < 2; ks++)
          aK[mt][ks] = *(const short8*)(ksrc + ks * 32 + quad * 8);
        float q = 0.f;
#pragma unroll
        for (int ks = 0; ks < 2; ks++)
#pragma unroll
          for (int j = 0; j < 8; j++) {
            float f = b2f((u16)aK[mt][ks][j]);
            q = fmaf(f, f, q);
          }
        q += __shfl_xor(q, 16, 64);
        q += __shfl_xor(q, 32, 64);
        nsk[mt] = 0.0625f * q;
      }
      f32x4 acc1[2][4] = {};
#pragma unroll
      for (int ks = 0; ks < 2; ks++)
#pragma unroll
        for (int mt = 0; mt < 2; mt++)
#pragma unroll
          for (int nt = 0; nt < 4; nt++)
            acc1[mt][nt] = __builtin_amdgcn_mfma_f32_16x16x32_bf16(
                aK[mt][ks], omB[nt][ks], acc1[mt][nt], 0, 0, 0);
#pragma unroll
      for (int mt = 0; mt < 2; mt++) {
        f32x4 nsv;
#pragma unroll
        for (int r = 0; r < 4; r++) nsv[r] = __shfl(nsk[mt], quad * 4 + r, 64);
#pragma unroll
        for (int nt = 0; nt < 4; nt++) {
          int m = w4 * 64 + nt * 16 + cl;
          u16 kf16[4];
#pragma unroll
          for (int r = 0; r < 4; r++)
            kf16[r] = f2b(__expf(acc1[mt][nt][r] - nsv[r]) * 0.0625f);
          uint2 pk;
          pk.x = (u32)kf16[0] | ((u32)kf16[1] << 16);
          pk.y = (u32)kf16[2] | ((u32)kf16[3] << 16);
          *(uint2*)(&KfT[g][m * 40 + mt * 16 + quad * 4]) = pk;
        }
      }
    }
    __syncthreads();   // VT[g] ready (written cross-wave); KfT[g] same-wave
    if (act) {
      short8 aF[4], bV[5];
#pragma unroll
      for (int mt2 = 0; mt2 < 4; mt2++)
        aF[mt2] = *(const short8*)(&KfT[g][(w4 * 64 + mt2 * 16 + cl) * 40 + quad * 8]);
#pragma unroll
      for (int nt2 = 0; nt2 < 5; nt2++)
        bV[nt2] = *(const short8*)(&VT[g][(nt2 * 16 + cl) * 40 + quad * 8]);
#pragma unroll
      for (int mt2 = 0; mt2 < 4; mt2++)
#pragma unroll
        for (int nt2 = 0; nt2 < 5; nt2++)
          acc2[mt2][nt2] = __builtin_amdgcn_mfma_f32_16x16x32_bf16(
              aF[mt2], bV[nt2], acc2[mt2][nt2], 0, 0, 0);
    }
  }
  // ---- cross-group reduction: group1 partials -> LDS staging -> group0 adds ----
  float* stg = (float*)&KfT[0][0];   // 20 KB chunks (KfT/VT dead now)
#pragma unroll
  for (int mt2 = 0; mt2 < 4; mt2++) {
    __syncthreads();
    if (g == 1) {
#pragma unroll
      for (int nt2 = 0; nt2 < 5; nt2++)
        *(f32x4*)&stg[((w4 * 5 + nt2) * 64 + lane) * 4] = acc2[mt2][nt2];
    }
    __syncthreads();
    if (g == 0) {
#pragma unroll
      for (int nt2 = 0; nt2 < 5; nt2++) {
        f32x4 o = *(const f32x4*)&stg[((w4 * 5 + nt2) * 64 + lane) * 4];
#pragma unroll
        for (int r = 0; r < 4; r++) acc2[mt2][nt2][r] += o[r];
      }
    }
  }
  if (g == 0) {
    u16* base = KVT_g + (size_t)bh * 80 * 256;
#pragma unroll
    for (int mt2 = 0; mt2 < 4; mt2++) {
      int m0 = w4 * 64 + mt2 * 16 + quad * 4;
#pragma unroll
      for (int nt2 = 0; nt2 < 4; nt2++) {
        u16 w[4];
#pragma unroll
        for (int r = 0; r < 4; r++) w[r] = f2b(acc2[mt2][nt2][r]);
        uint2 pk;
        pk.x = (u32)w[0] | ((u32)w[1] << 16);
        pk.y = (u32)w[2] | ((u32)w[3] << 16);
        *(uint2*)(&base[(size_t)(nt2 * 16 + cl) * 256 + m0]) = pk;
      }
      if (cl == 0) {
        u16 w[4];
#pragma unroll
        for (int r = 0; r < 4; r++) w[r] = f2b(acc2[mt2][4][r]);
        uint2 pk;
        pk.x = (u32)w[0] | ((u32)w[1] << 16);
        pk.y = (u32)w[2] | ((u32)w[3] << 16);
        *(uint2*)(&base[(size_t)64 * 256 + m0]) = pk;
      }
    }
  }
}

// ---------------- Performer out via MFMA ----------------
__global__ __launch_bounds__(256) void attn_out_mfma(
    u16* __restrict__ Qb, const u16* __restrict__ KVT_g,
    const u16* __restrict__ omt) {
  int bh = blockIdx.x; int b = bh >> 3, h = bh & 7;
  int chunk = blockIdx.y;
  int tid = threadIdx.x;
  int wid = tid >> 6, lane = tid & 63;
  int quad = lane >> 4, cl = lane & 15;
  __shared__ u16 smem[64 * 264 + 80 * 264];
  u16* Qf = smem;
  u16* KVT = smem + 64 * 264;

  const u16* kvsrc = KVT_g + (size_t)bh * 80 * 256;
#pragma unroll
  for (int i = 0; i < 9; i++) {
    int idx = tid + i * 256;
    if (idx < 2080) {
      int row = idx >> 5, c8 = (idx & 31) * 8;
      *(uint4*)(&KVT[row * 264 + c8]) = *(const uint4*)(kvsrc + (size_t)row * 256 + c8);
    }
  }

  short8 omB[4][2];
#pragma unroll
  for (int nt = 0; nt < 4; nt++)
#pragma unroll
    for (int ks = 0; ks < 2; ks++)
      omB[nt][ks] = *(const short8*)(omt + (size_t)(wid * 64 + nt * 16 + cl) * 64
                                         + ks * 32 + quad * 8);

  int t0 = chunk * 64;
  short8 aQ[4][2];
  float nss[4];
#pragma unroll
  for (int mt = 0; mt < 4; mt++) {
    int tglob = t0 + mt * 16 + cl;
    int trow = tglob < LL ? tglob : LL - 1;
    const u16* qsrc = Qb + ((size_t)(b * LL + trow)) * DD + h * DHH;
#pragma unroll
    for (int ks = 0; ks < 2; ks++)
      aQ[mt][ks] = *(const short8*)(qsrc + ks * 32 + quad * 8);
    float q = 0.f;
#pragma unroll
    for (int ks = 0; ks < 2; ks++)
#pragma unroll
      for (int j = 0; j < 8; j++) {
        float f = b2f((u16)aQ[mt][ks][j]);
        q = fmaf(f, f, q);
      }
    q += __shfl_xor(q, 16, 64);
    q += __shfl_xor(q, 32, 64);
    nss[mt] = 0.0625f * q;
  }

  f32x4 acc1[4][4] = {};
#pragma unroll
  for (int ks = 0; ks < 2; ks++)
#pragma unroll
    for (int mt = 0; mt < 4; mt++)
#pragma unroll
      for (int nt = 0; nt < 4; nt++)
        acc1[mt][nt] = __builtin_amdgcn_mfma_f32_16x16x32_bf16(
            omB[nt][ks], aQ[mt][ks], acc1[mt][nt], 0, 0, 0);
#pragma unroll
  for (int mt = 0; mt < 4; mt++) {
#pragma unroll
    for (int nt = 0; nt < 4; nt++) {
      u16 w[4];
#pragma unroll
      for (int r = 0; r < 4; r++)
        w[r] = f2b(__expf(acc1[mt][nt][r] - nss[mt]) * 0.0625f);
      uint2 pk;
      pk.x = (u32)w[0] | ((u32)w[1] << 16);
      pk.y = (u32)w[2] | ((u32)w[3] << 16);
      *(uint2*)(&Qf[(mt * 16 + cl) * 264 + wid * 64 + nt * 16 + quad * 4]) = pk;
    }
  }
  __syncthreads();
  f32x4 acc2[5] = {};
#pragma unroll
  for (int ks2 = 0; ks2 < 8; ks2++) {
    short8 aF = *(const short8*)(&Qf[(wid * 16 + cl) * 264 + ks2 * 32 + quad * 8]);
#pragma unroll
    for (int nt2 = 0; nt2 < 5; nt2++) {
      short8 bK = *(const short8*)(&KVT[(nt2 * 16 + cl) * 264 + ks2 * 32 + quad * 8]);
      acc2[nt2] = __builtin_amdgcn_mfma_f32_16x16x32_bf16(bK, aF, acc2[nt2], 0, 0, 0);
    }
  }
  float nval = __shfl(acc2[4][0], cl, 64);
  float inv = 1.0f / fmaxf(nval, 1e-6f);
  int tglob = t0 + wid * 16 + cl;
  if (tglob < LL) {
    u16* dst = Qb + ((size_t)(b * LL + tglob)) * DD + h * DHH;
#pragma unroll
    for (int nt2 = 0; nt2 < 4; nt2++) {
      u16 w[4];
#pragma unroll
      for (int r = 0; r < 4; r++) w[r] = f2b(acc2[nt2][r] * inv);
      uint2 pk;
      pk.x = (u32)w[0] | ((u32)w[1] << 16);
      pk.y = (u32)w[2] | ((u32)w[3] << 16);
      *(uint2*)(dst + nt2 * 16 + quad * 4) = pk;
    }
  }
}

// ---------------- pooling ----------------
__global__ __launch_bounds__(256) void softmax_kernel(const float* __restrict__ sc,
    float* __restrict__ alpha) {
  __shared__ float sm[4];
  int b = blockIdx.x, tid = threadIdx.x;
  float mx = -1e30f;
  for (int i = tid; i < LL; i += 256) mx = fmaxf(mx, sc[b * LL + i]);
#pragma unroll
  for (int o = 32; o; o >>= 1) mx = fmaxf(mx, __shfl_down(mx, o, 64));
  if ((tid & 63) == 0) sm[tid >> 6] = mx;
  __syncthreads();
  mx = fmaxf(fmaxf(sm[0], sm[1]), fmaxf(sm[2], sm[3]));
  float s = 0.f;
  for (int i = tid; i < LL; i += 256) {
    float e = expf(sc[b * LL + i] - mx);
    alpha[b * LL + i] = e;
    s += e;
  }
  __syncthreads();
#pragma unroll
  for (int o = 32; o; o >>= 1) s += __shfl_down(s, o, 64);
  if ((tid & 63) == 0) sm[tid >> 6] = s;
  __syncthreads();
  float invs = 1.f / (sm[0] + sm[1] + sm[2] + sm[3]);
  for (int i = tid; i < LL; i += 256) alpha[b * LL + i] *= invs;
}

// attentive-pool partials: grid (BB, 8), each block covers 100 tokens
__global__ __launch_bounds__(512) void pool_part_kernel(const u16* __restrict__ h,
    const float* __restrict__ alpha, float* __restrict__ pmu, float* __restrict__ pm2) {
  int b = blockIdx.x, seg = blockIdx.y, d = threadIdx.x;
  const u16* hb = h + (size_t)b * LL * DD + (size_t)seg * 100 * DD + d;
  const float* ab = alpha + b * LL + seg * 100;
  float mu = 0.f, m2 = 0.f;
  for (int l = 0; l < 100; l++) {
    float a = ab[l], v = b2f(hb[(size_t)l * DD]);
    mu = fmaf(a, v, mu);
    m2 = fmaf(a * v, v, m2);
  }
  pmu[((size_t)seg * BB + b) * DD + d] = mu;
  pm2[((size_t)seg * BB + b) * DD + d] = m2;
}

__global__ __launch_bounds__(512) void pool_reduce_kernel(const float* __restrict__ pmu,
    const float* __restrict__ pm2, float* __restrict__ feat) {
  int b = blockIdx.x, d = threadIdx.x;
  float mu = 0.f, m2 = 0.f;
#pragma unroll
  for (int s = 0; s < 8; s++) {
    mu += pmu[((size_t)s * BB + b) * DD + d];
    m2 += pm2[((size_t)s * BB + b) * DD + d];
  }
  feat[b * 2 * DD + d] = mu;
  feat[b * 2 * DD + DD + d] = sqrtf(fmaxf(m2 - mu * mu, 1e-8f));
}

__global__ __launch_bounds__(320) void head_kernel(const float* __restrict__ feat,
    const void* __restrict__ hw, const void* __restrict__ hb, void* out,
    const u32* __restrict__ dflag) {
  int flag = (int)dflag[0];
  int b = blockIdx.x;
  int t = threadIdx.x;
  int n = t >> 5, j0 = t & 31;
  float p = 0.f;
  for (int j = j0; j < 2 * DD; j += 32)
    p = fmaf(feat[b * 2 * DD + j], ldx(hw, (size_t)j * NCLS + n, flag), p);
#pragma unroll
  for (int o = 16; o; o >>= 1) p += __shfl_down(p, o, 32);
  if (j0 == 0) {
    float v = p + ldx(hb, n, flag);
    if (flag) ((u16*)out)[b * NCLS + n] = f2b(v);
    else ((float*)out)[b * NCLS + n] = v;
  }
}

// ---------------- host launch ----------------
extern "C" void kernel_launch(void* const* d_in, const int* in_sizes, int n_in,
                              void* d_out, int out_size, void* d_ws, size_t ws_size,
                              hipStream_t stream) {
  char* ws = (char*)d_ws;
  size_t off = 0;
  auto alloc = [&](size_t bytes) -> char* {
    char* p = ws + off;
    off += (bytes + 255) & ~(size_t)255;
    return p;
  };
  u16* hbuf = (u16*)alloc((size_t)BL * DD * 2);
  u16* buf1 = (u16*)alloc((size_t)BL * DD * 2);
  u16* buf2 = (u16*)alloc((size_t)BL * DD * 2);
  u16* KVT_g = (u16*)alloc((size_t)BB * HH * 80 * 256 * 2);
  float* muv = (float*)alloc((size_t)BL * 4);
  float* rinvv = (float*)alloc((size_t)BL * 4);
  float* scores = (float*)alloc((size_t)BL * 4);
  float* alpha = (float*)alloc((size_t)BL * 4);
  float* feat = (float*)alloc((size_t)BB * 2 * DD * 4);
  float* uvec = (float*)alloc((size_t)NUC * 4);
  float* cvec = (float*)alloc((size_t)NUC * 4);
  float* pU = (float*)alloc((size_t)8 * NUC * 4);
  float* pC = (float*)alloc((size_t)8 * NUC * 4);
  float* pSum = (float*)alloc((size_t)8 * BL * 4);
  float* pSsq = (float*)alloc((size_t)8 * BL * 4);
  u16* ombT = (u16*)alloc((size_t)NLAYER * MM * DHH * 2);
  u16* wtall = (u16*)alloc((size_t)WT_TOTAL * 2);
  u32* dflag = (u32*)alloc(256);
  size_t off_base = off;
  u16* bufQ = (u16*)alloc((size_t)BL * DD * 2);       // fused-QKV Q buffer (ws-gated)
  size_t off_full = off;

  if (ws_size < off_base) {
    sentinel_kernel<<<2, 256, 0, stream>>>((u16*)d_out, out_size);
    return;
  }
  const bool fused = (ws_size >= off_full);

  const void* x       = d_in[0];
  const void* patchW  = d_in[1];
  const void* patchb  = d_in[2];
  const void* patchg  = d_in[3];
  const void* patchbe = d_in[4];
  const void* ln1g    = d_in[5];
  const void* ln1b    = d_in[6];
  const void* qW      = d_in[7];
  const void* kW      = d_in[8];
  const void* vW      = d_in[9];
  const void* oW      = d_in[10];
  const void* ob      = d_in[11];
  const void* omg     = d_in[12];
  const void* ln2g    = d_in[13];
  const void* ln2b    = d_in[14];
  const void* f1W     = d_in[15];
  const void* f1b     = d_in[16];
  const void* f2W     = d_in[17];
  const void* f2b_    = d_in[18];
  const void* poolW1  = d_in[19];
  const void* poolW2  = d_in[20];
  const void* headW   = d_in[21];
  const void* headb   = d_in[22];

  sniff_kernel<<<1, 64, 0, stream>>>((const u32*)patchg, dflag);

  patchify_kernel<<<(BL * KPATCH) / 256, 256, 0, stream>>>(x, buf1, dflag);
  omcvt_kernel<<<(NLAYER * MM * DHH + 255) / 256, 256, 0, stream>>>(omg, ombT, dflag);
  // ALL weight transposes + LN-fold partials in one dispatch
  megawt_kernel<<<1072, 256, 0, stream>>>(patchW, qW, kW, vW, oW, f1W, f2W, poolW1,
                                          ln1g, ln1b, ln2g, ln2b, wtall, pU, pC, dflag);
  ucr_kernel<<<NUC / 256, 256, 0, stream>>>(pU, pC, uvec, cvec, NUC);

  // patch GEMM (+stats of its output) -> ln_apply (stats-in from pS, stats-out muv/rinvv)
  mgemm<0, true, false, 0, false, true, false><<<dim3(4, 200), 256, 0, stream>>>(
      buf1, wtall + WT_PATCH, patchb, 0, nullptr, nullptr, nullptr, nullptr,
      nullptr, buf2, nullptr, nullptr, pSum, pSsq, KPATCH, DD, dflag);
  ln_apply_kernel<<<BL / 4, 256, 0, stream>>>(buf2, pSum, pSsq, patchg, patchbe,
                                              hbuf, muv, rinvv, dflag);

  for (int l = 0; l < NLAYER; l++) {
    size_t oD = (size_t)l * DD;
    size_t oF = (size_t)l * FF;
    const u16* omtl = ombT + (size_t)l * MM * DHH;
    const u16* qkvT = wtall + (l == 0 ? WT_QKV0 : WT_QKV1);
    const u16* oWT  = wtall + (l == 0 ? WT_OW0 : WT_OW1);
    const u16* f1T  = wtall + (l == 0 ? WT_F10 : WT_F11);
    const u16* f2T  = wtall + (l == 0 ? WT_F20 : WT_F21);
    const float* uq = uvec + (l == 0 ? 0 : 2560);
    const float* cq = cvec + (l == 0 ? 0 : 2560);
    const float* uf = uvec + (l == 0 ? 1536 : 4096);
    const float* cf = cvec + (l == 0 ? 1536 : 4096);

    u16* qb;
    if (fused) {
      if (l == 0)
        mgemm<0, false, false, 1, true, false, false><<<dim3(12, 200), 256, 0, stream>>>(
            hbuf, qkvT, nullptr, 0, muv, rinvv, uq, cq, nullptr,
            buf1, buf2, bufQ, nullptr, nullptr, DD, 3 * DD, dflag);
      else
        mgemm<0, false, false, 2, true, false, false><<<dim3(12, 200), 256, 0, stream>>>(
            hbuf, qkvT, nullptr, 0, pSum, pSsq, uq, cq, nullptr,
            buf1, buf2, bufQ, nullptr, nullptr, DD, 3 * DD, dflag);
      kv_kernel_mfma<<<BB * HH, 512, 0, stream>>>(buf1, buf2, omtl, KVT_g);
      qb = bufQ;
    } else {
      // non-fused: K, V, kv, then Q into buf1
      if (l == 0) {
        mgemm<0, false, false, 1, false, false, false><<<dim3(4, 200), 256, 0, stream>>>(
            hbuf, qkvT, nullptr, 0, muv, rinvv, uq, cq, nullptr,
            buf1, nullptr, nullptr, nullptr, nullptr, DD, DD, dflag);
        mgemm<0, false, false, 1, false, false, false><<<dim3(4, 200), 256, 0, stream>>>(
            hbuf, qkvT + 262144, nullptr, 0, muv, rinvv, uq + 512, cq + 512, nullptr,
            buf2, nullptr, nullptr, nullptr, nullptr, DD, DD, dflag);
      } else {
        mgemm<0, false, false, 2, false, false, false><<<dim3(4, 200), 256, 0, stream>>>(
            hbuf, qkvT, nullptr, 0, pSum, pSsq, uq, cq, nullptr,
            buf1, nullptr, nullptr, nullptr, nullptr, DD, DD, dflag);
        mgemm<0, false, false, 2, false, false, false><<<dim3(4, 200), 256, 0, stream>>>(
            hbuf, qkvT + 262144, nullptr, 0, pSum, pSsq, uq + 512, cq + 512, nullptr,
            buf2, nullptr, nullptr, nullptr, nullptr, DD, DD, dflag);
      }
      kv_kernel_mfma<<<BB * HH, 512, 0, stream>>>(buf1, buf2, omtl, KVT_g);
      if (l == 0)
        mgemm<0, false, false, 1, false, false, false><<<dim3(4, 200), 256, 0, stream>>>(
            hbuf, qkvT + 524288, nullptr, 0, muv, rinvv, uq + 1024, cq + 1024, nullptr,
            buf1, nullptr, nullptr, nullptr, nullptr, DD, DD, dflag);
      else
        mgemm<0, false, false, 2, false, false, false><<<dim3(4, 200), 256, 0, stream>>>(
            hbuf, qkvT + 524288, nullptr, 0, pSum, pSsq, uq + 1024, cq + 1024, nullptr,
            buf1, nullptr, nullptr, nullptr, nullptr, DD, DD, dflag);
      qb = buf1;
    }
    attn_out_mfma<<<dim3(BB * HH, 13), 256, 0, stream>>>(qb, KVT_g, omtl);
    // h += attn @ oW + ob  (+ stats of new h for LN2)
    mgemm<0, true, true, 0, false, true, false><<<dim3(4, 200), 256, 0, stream>>>(
        qb, oWT, ob, oD, nullptr, nullptr, nullptr, nullptr,
        hbuf, hbuf, nullptr, nullptr, pSum, pSsq, DD, DD, dflag);
    // FFN: f1 (LN2 folded via pS) -> f2 (+res; stats only if feeding next layer's LN1)
    mgemm<1, true, false, 2, false, false, false><<<dim3(8, 200), 256, 0, stream>>>(
        hbuf, f1T, f1b, oF, pSum, pSsq, uf, cf, nullptr,
        buf1, nullptr, nullptr, nullptr, nullptr, DD, FF, dflag);
    if (l == 0)
      mgemm<0, true, true, 0, false, true, false><<<dim3(4, 200), 256, 0, stream>>>(
          buf1, f2T, f2b_, oD, nullptr, nullptr, nullptr, nullptr,
          hbuf, hbuf, nullptr, nullptr, pSum, pSsq, FF, DD, dflag);
    else
      mgemm<0, true, true, 0, false, false, false><<<dim3(4, 200), 256, 0, stream>>>(
          buf1, f2T, f2b_, oD, nullptr, nullptr, nullptr, nullptr,
          hbuf, hbuf, nullptr, nullptr, nullptr, nullptr, FF, DD, dflag);
  }

  // pool GEMM with fused tanh + score (dot with poolW2) -> scores; no tile store
  mgemm<2, false, false, 0, false, false, true><<<dim3(1, 200), 256, 0, stream>>>(
      hbuf, wtall + WT_POOL, poolW2, 0, nullptr, nullptr, nullptr, nullptr,
      nullptr, nullptr, nullptr, nullptr, scores, nullptr, DD, HIDP, dflag);
  softmax_kernel<<<BB, 256, 0, stream>>>(scores, alpha);
  // attentive-stats pooling: partials (reuse pSum/pSsq, free by now) + reduce
  pool_part_kernel<<<dim3(BB, 8), 512, 0, stream>>>(hbuf, alpha, pSum, pSsq);
  pool_reduce_kernel<<<BB, 512, 0, stream>>>(pSum, pSsq, feat);
  head_kernel<<<BB, 320, 0, stream>>>(feat, headW, headb, d_out, dflag);
}